// Round 1
// baseline (107.817 us; speedup 1.0000x reference)
//
#include <hip/hip_runtime.h>
#include <hip/hip_bf16.h>
#include <stdint.h>

// C = (B,16,16): diag (k,k) = sigmoid(x·Wd[k]+bd[k]); off (i,j) = -softplus(x·Wo[r]+bo[r])
// => permuted GEMM: out[b][c] with c=i*16+j, W row permuted, activation by (c%17==0).
// M=65536 N=256 K=1024. bf16 MFMA 16x16x32, BM=128, BK=64, 8 waves (2Mx4N).

typedef __bf16 bf16x8 __attribute__((ext_vector_type(8)));
typedef float f32x4 __attribute__((ext_vector_type(4)));

#define THREADS 512
#define BM 128
#define KSTEPS 16       // 1024 / 64
#define WTILE 32768     // 256 cols x 64 k x 2B, one pre-swizzled LDS image per K-step
#define WBYTES (WTILE * KSTEPS)   // 512 KiB

__device__ __forceinline__ unsigned bf_rtne(unsigned u) {
  return (u + 0x7fffu + ((u >> 16) & 1u)) >> 16;
}
__device__ __forceinline__ unsigned pack2(float lo, float hi) {
  return bf_rtne(__float_as_uint(lo)) | (bf_rtne(__float_as_uint(hi)) << 16);
}

__device__ __forceinline__ void gload_lds16(const void* g, void* l) {
  __builtin_amdgcn_global_load_lds(
      (const __attribute__((address_space(1))) unsigned int*)g,
      (__attribute__((address_space(3))) unsigned int*)l, 16, 0, 0);
}

// Build permuted, bf16-converted, pre-swizzled weight images + bias vector in d_ws.
// Image layout per K-step: byte = (c*128 + k*2) ^ ((c&7)<<4)  (16B-granule XOR swizzle)
__global__ void prep_kernel(const float* __restrict__ Wd, const float* __restrict__ bd,
                            const float* __restrict__ Wo, const float* __restrict__ bo,
                            char* __restrict__ wbuf, float* __restrict__ bias) {
  const int c = blockIdx.x;    // 0..255 output col
  const int t = threadIdx.x;   // 0..255, 4 k-elems each
  const int i = c >> 4, j = c & 15;
  const float* src;
  float b;
  if (i == j) { src = Wd + i * 1024; b = bd[i]; }
  else { int r = i * 15 + (j < i ? j : j - 1); src = Wo + r * 1024; b = bo[r]; }
  if (t == 0) bias[c] = b;
  const int kk = t * 4;
  const int kstep = kk >> 6, k6 = kk & 63;
  float4 v = *reinterpret_cast<const float4*>(src + kk);
  uint2 h;
  h.x = pack2(v.x, v.y);
  h.y = pack2(v.z, v.w);
  const unsigned off = (unsigned)((c * 128 + k6 * 2) ^ ((c & 7) << 4));
  *reinterpret_cast<uint2*>(wbuf + kstep * WTILE + off) = h;
}

__global__ __launch_bounds__(THREADS, 2) void cap_main(
    const float* __restrict__ x, const char* __restrict__ wbuf,
    const float* __restrict__ bias, float* __restrict__ out) {
  __shared__ char smem[98304];  // As[2]:2x16K  Ws[2]:2x32K

  const int tid = threadIdx.x;
  const int wid = tid >> 6;
  const int lane = tid & 63;
  const int l15 = lane & 15;
  const int l4 = lane >> 4;
  const int wm = wid >> 2;  // 0..1  (64 rows each)
  const int wn = wid & 3;   // 0..3  (64 cols each)

  const size_t blkRow = (size_t)blockIdx.x * BM;

  // A staging: 2 chunks of 8 consecutive floats per thread over the 128x64 tile
  const int f0 = tid * 8;
  const int f1 = f0 + 4096;
  const int ar0 = f0 >> 6, ac0 = f0 & 63;
  const int ar1 = f1 >> 6, ac1 = f1 & 63;
  const float* xs0 = x + (blkRow + (size_t)ar0) * 1024 + ac0;
  const float* xs1 = x + (blkRow + (size_t)ar1) * 1024 + ac1;
  const unsigned aw0 = (unsigned)((ar0 * 128 + ac0 * 2) ^ ((ar0 & 7) << 4));
  const unsigned aw1 = (unsigned)((ar1 * 128 + ac1 * 2) ^ ((ar1 & 7) << 4));

  // fragment read bases (A: row = wm*64+fm*16+l15, k-bytes = ks*64 + l4*16)
  const unsigned abase = (unsigned)((wm * 64 + l15) * 128 + l4 * 16);
  const unsigned bbase = (unsigned)((wn * 64 + l15) * 128 + l4 * 16);
  const unsigned sxor = (unsigned)((l15 & 7) << 4);

  f32x4 acc[4][4];
#pragma unroll
  for (int m = 0; m < 4; ++m)
#pragma unroll
    for (int n = 0; n < 4; ++n) acc[m][n] = (f32x4){0.f, 0.f, 0.f, 0.f};

  // ---- prologue: stage tile 0 ----
  {
    float4 p0 = *reinterpret_cast<const float4*>(xs0);
    float4 p1 = *reinterpret_cast<const float4*>(xs0 + 4);
    float4 p2 = *reinterpret_cast<const float4*>(xs1);
    float4 p3 = *reinterpret_cast<const float4*>(xs1 + 4);
    char* Wn0 = smem + 32768;
#pragma unroll
    for (int r = 0; r < 4; ++r)
      gload_lds16(wbuf + r * 8192 + wid * 1024 + lane * 16, Wn0 + r * 8192 + wid * 1024);
    uint4 w0, w1;
    w0.x = pack2(p0.x, p0.y); w0.y = pack2(p0.z, p0.w);
    w0.z = pack2(p1.x, p1.y); w0.w = pack2(p1.z, p1.w);
    w1.x = pack2(p2.x, p2.y); w1.y = pack2(p2.z, p2.w);
    w1.z = pack2(p3.x, p3.y); w1.w = pack2(p3.z, p3.w);
    *reinterpret_cast<uint4*>(smem + aw0) = w0;
    *reinterpret_cast<uint4*>(smem + aw1) = w1;
  }
  __syncthreads();

  for (int t = 0; t < KSTEPS; ++t) {
    const int cur = t & 1;
    const char* Ac = smem + cur * 16384;
    const char* Bc = smem + 32768 + cur * 32768;
    char* An = smem + (cur ^ 1) * 16384;
    char* Wn = smem + 32768 + (cur ^ 1) * 32768;

    float4 n0, n1, n2, n3;
    if (t + 1 < KSTEPS) {
      const float* s0 = xs0 + (t + 1) * 64;
      const float* s1 = xs1 + (t + 1) * 64;
      n0 = *reinterpret_cast<const float4*>(s0);
      n1 = *reinterpret_cast<const float4*>(s0 + 4);
      n2 = *reinterpret_cast<const float4*>(s1);
      n3 = *reinterpret_cast<const float4*>(s1 + 4);
      const char* wsp = wbuf + (t + 1) * WTILE;
#pragma unroll
      for (int r = 0; r < 4; ++r)
        gload_lds16(wsp + r * 8192 + wid * 1024 + lane * 16, Wn + r * 8192 + wid * 1024);
    }

#pragma unroll
    for (int ks = 0; ks < 2; ++ks) {
      bf16x8 af[4], bfr[4];
#pragma unroll
      for (int m = 0; m < 4; ++m)
        af[m] = *reinterpret_cast<const bf16x8*>(Ac + ((abase + m * 2048 + ks * 64) ^ sxor));
#pragma unroll
      for (int n = 0; n < 4; ++n)
        bfr[n] = *reinterpret_cast<const bf16x8*>(Bc + ((bbase + n * 2048 + ks * 64) ^ sxor));
#pragma unroll
      for (int m = 0; m < 4; ++m)
#pragma unroll
        for (int n = 0; n < 4; ++n)
          acc[m][n] = __builtin_amdgcn_mfma_f32_16x16x32_bf16(af[m], bfr[n], acc[m][n], 0, 0, 0);
    }

    if (t + 1 < KSTEPS) {
      uint4 w0, w1;
      w0.x = pack2(n0.x, n0.y); w0.y = pack2(n0.z, n0.w);
      w0.z = pack2(n1.x, n1.y); w0.w = pack2(n1.z, n1.w);
      w1.x = pack2(n2.x, n2.y); w1.y = pack2(n2.z, n2.w);
      w1.z = pack2(n3.x, n3.y); w1.w = pack2(n3.z, n3.w);
      *reinterpret_cast<uint4*>(An + aw0) = w0;
      *reinterpret_cast<uint4*>(An + aw1) = w1;
    }
    __syncthreads();
  }

  // ---- epilogue: bias + activation + store ----
#pragma unroll
  for (int n = 0; n < 4; ++n) {
    const int col = wn * 64 + n * 16 + l15;
    const float bs = bias[col];
    const bool diag = (col % 17) == 0;
#pragma unroll
    for (int m = 0; m < 4; ++m) {
      const size_t row0 = blkRow + (size_t)(wm * 64 + m * 16 + l4 * 4);
#pragma unroll
      for (int j2 = 0; j2 < 4; ++j2) {
        float v = acc[m][n][j2] + bs;
        float e = __expf(-fabsf(v));
        float sig = (v >= 0.f) ? 1.f / (1.f + e) : e / (1.f + e);
        float sp = fmaxf(v, 0.f) + __logf(1.f + e);
        out[(row0 + j2) * 256 + col] = diag ? sig : -sp;
      }
    }
  }
}

extern "C" void kernel_launch(void* const* d_in, const int* in_sizes, int n_in,
                              void* d_out, int out_size, void* d_ws, size_t ws_size,
                              hipStream_t stream) {
  const float* x = (const float*)d_in[0];
  const float* Wd = (const float*)d_in[1];
  const float* bd = (const float*)d_in[2];
  const float* Wo = (const float*)d_in[3];
  const float* bo = (const float*)d_in[4];
  float* out = (float*)d_out;
  char* wbuf = (char*)d_ws;                  // 512 KiB weight images
  float* bias = (float*)(wbuf + WBYTES);     // 1 KiB bias

  prep_kernel<<<dim3(256), dim3(256), 0, stream>>>(Wd, bd, Wo, bo, wbuf, bias);
  cap_main<<<dim3(512), dim3(THREADS), 0, stream>>>(x, wbuf, bias, out);
}